// Round 2
// baseline (84.588 us; speedup 1.0000x reference)
//
#include <hip/hip_runtime.h>
#include <hip/hip_bf16.h>
#include <cstdint>
#include <cstddef>

#define NRES 1024
#define NB 16
#define ADIM 64
#define ODIM 256
#define TOTROWS 9408   // sum(RES_LEN)*64 = 147*64

typedef __bf16 bf16x8 __attribute__((ext_vector_type(8)));
typedef float f32x4 __attribute__((ext_vector_type(4)));

// ---------------- compile-time replication of np.random.default_rng(42) ----------------
struct Meta {
    uint16_t start[NRES];
    uint8_t  letter[NRES];
    int atoms;
};

constexpr int RES_LEN_A[20] = {4,10,7,7,5,8,8,3,9,7,7,8,7,10,6,5,6,13,11,6}; // ARNDCQEGHILKMFPSTWYV

constexpr uint32_t ss_hash(uint32_t value, uint32_t& hc) {
    value ^= hc;
    hc *= 0x931e8875u;   // MULT_A
    value *= hc;
    value ^= value >> 16;
    return value;
}
// numpy bit_generator.pyx mix(): MIX_MULT_L*x - MIX_MULT_R*y  (subtraction!)
constexpr uint32_t ss_mix(uint32_t x, uint32_t y) {
    uint32_t r = 0xca01f9ddu * x - 0x4973f715u * y;
    r ^= r >> 16;
    return r;
}

constexpr Meta make_meta() {
    Meta m = {};
    // SeedSequence(42): pool_size 4, entropy=[42]
    uint32_t pool[4] = {0,0,0,0};
    uint32_t hc = 0x43b0d7e5u;   // INIT_A
    pool[0] = ss_hash(42u, hc);
    pool[1] = ss_hash(0u, hc);
    pool[2] = ss_hash(0u, hc);
    pool[3] = ss_hash(0u, hc);
    for (int s = 0; s < 4; ++s)
        for (int d = 0; d < 4; ++d)
            if (s != d) pool[d] = ss_mix(pool[d], ss_hash(pool[s], hc));
    // generate_state(4, uint64) -> 8 x uint32, little-endian pairs
    uint32_t hb = 0x8b51f9ddu;   // INIT_B
    uint64_t w[8] = {};
    for (int i = 0; i < 8; ++i) {
        uint32_t dv = pool[i & 3] ^ hb;
        hb *= 0x58f38dedu;       // MULT_B
        dv *= hb;
        dv ^= dv >> 16;
        w[i] = dv;
    }
    uint64_t s64[4] = {};
    for (int i = 0; i < 4; ++i) s64[i] = w[2*i] | (w[2*i+1] << 32);
    // PCG64 setseq-128: seed[0]=state_hi, seed[1]=state_lo, seed[2]=inc_hi, seed[3]=inc_lo
    using u128 = unsigned __int128;
    const u128 MULT = ((u128)2549297995355413924ULL << 64) | (u128)4865540595714422341ULL;
    u128 initstate = ((u128)s64[0] << 64) | (u128)s64[1];
    u128 initseq   = ((u128)s64[2] << 64) | (u128)s64[3];
    u128 inc = (initseq << 1) | (u128)1;
    u128 state = inc;            // state=0; step -> state=inc
    state += initstate;
    state = state * MULT + inc;  // second step
    bool has32 = false;
    uint32_t cached = 0;
    int atoms = 0;
    for (int i = 0; i < NRES; ++i) {
        uint32_t res = 0;
        while (true) {
            uint32_t r32;
            if (has32) { r32 = cached; has32 = false; }
            else {
                state = state * MULT + inc;                  // step
                uint64_t hi = (uint64_t)(state >> 64);
                uint64_t lo = (uint64_t)state;
                uint32_t rot = (uint32_t)(state >> 122);
                uint64_t v = hi ^ lo;
                uint64_t o64 = (v >> rot) | (v << ((64u - rot) & 63u)); // rotr
                cached = (uint32_t)(o64 >> 32);   // PCG64 next32 buffers HIGH half
                has32 = true;
                r32 = (uint32_t)o64;              // returns LOW half first
            }
            // numpy bounded_lemire_uint32: accept iff low32(r*20) >= (2^32-20)%20 == 16
            uint64_t mm = (uint64_t)r32 * 20ull;
            uint32_t leftover = (uint32_t)mm;
            if (leftover >= 16u) { res = (uint32_t)(mm >> 32); break; }
        }
        m.letter[i] = (uint8_t)res;
        m.start[i] = (uint16_t)atoms;
        atoms += RES_LEN_A[res];
    }
    m.atoms = atoms;
    return m;
}

constexpr Meta H_META = make_meta();

struct LetterTab {
    int woff[21];   // cumulative W row offsets; woff[20] = 9408
    int fan[20];
};
constexpr LetterTab make_tab() {
    LetterTab t = {};
    int off = 0;
    for (int l = 0; l < 20; ++l) {
        t.woff[l] = off;
        t.fan[l] = RES_LEN_A[l] * ADIM;
        off += t.fan[l];
    }
    t.woff[20] = off;
    return t;
}
constexpr LetterTab H_TAB = make_tab();

__constant__ Meta g_meta = make_meta();
__constant__ LetterTab g_tab = make_tab();

// Transposed bf16 weights: per letter block, layout [n (256)][k (fan)], i.e. B^T.
__device__ __bf16 g_Wt[(size_t)TOTROWS * ODIM];

// ---------------- prep: W (fp32 row-major) -> g_Wt (bf16, per-letter transposed) ----------------
__global__ __launch_bounds__(256) void prep_W_kernel(const float* __restrict__ W) {
    const int k = blockIdx.x;                   // global W row, 0..9407
    int l = 0;
    while (k >= g_tab.woff[l + 1]) ++l;         // letter for this row (uniform per block)
    const int kl = k - g_tab.woff[l];
    const int fan = g_tab.fan[l];
    const size_t base = (size_t)g_tab.woff[l] * ODIM;
    const int n = threadIdx.x;
    const float v = W[(size_t)k * ODIM + n];    // coalesced row read
    g_Wt[base + (size_t)n * fan + kl] = (__bf16)v;
}

// ---------------- main: per-residue 48x256 GEMM via bf16 MFMA ----------------
__global__ __launch_bounds__(256) void lin_mfma_kernel(const float* __restrict__ x,
                                                       float* __restrict__ out,
                                                       int atoms) {
    const int p = blockIdx.x;
    const int letter = g_meta.letter[p];
    const int start = g_meta.start[p];
    const int fan = g_tab.fan[letter];          // multiple of 64
    const size_t wt_base = (size_t)g_tab.woff[letter] * ODIM;

    const int tid = threadIdx.x;
    const int lane = tid & 63;
    const int wv = tid >> 6;        // wave 0..3 -> output cols [64*wv, 64*wv+64)
    const int l15 = lane & 15;
    const int g4 = lane >> 4;       // k-group 0..3

    __shared__ __align__(16) __bf16 As[48][72];   // rows m=b*3+i, 64 k-chunk + pad(8)

    f32x4 acc[3][4];
    #pragma unroll
    for (int t = 0; t < 3; ++t)
        #pragma unroll
        for (int nt = 0; nt < 4; ++nt)
            acc[t][nt] = (f32x4){0.f, 0.f, 0.f, 0.f};

    for (int k0 = 0; k0 < fan; k0 += 64) {
        __syncthreads();
        // stage A chunk: 16 batches x 192 consecutive floats each (= 64 k x 3 i), fp32->bf16
        #pragma unroll
        for (int jj = 0; jj < 3; ++jj) {
            const int e4 = tid + 256 * jj;          // 0..767 float4s
            const int b = e4 / 48;
            const int r4 = e4 - b * 48;
            const float4 v = *(const float4*)&x[((size_t)b * atoms + start) * 192 + (size_t)k0 * 3 + (size_t)r4 * 4];
            const float vv[4] = {v.x, v.y, v.z, v.w};
            #pragma unroll
            for (int q = 0; q < 4; ++q) {
                const int r = r4 * 4 + q;           // = kl*3 + i
                const int kl = r / 3;
                const int i = r - kl * 3;
                As[b * 3 + i][kl] = (__bf16)vv[q];
            }
        }
        __syncthreads();
        #pragma unroll
        for (int h = 0; h < 2; ++h) {
            const int kh = h * 32;
            bf16x8 a[3], bfr[4];
            #pragma unroll
            for (int t = 0; t < 3; ++t)
                a[t] = *(const bf16x8*)&As[t * 16 + l15][kh + g4 * 8];
            #pragma unroll
            for (int nt = 0; nt < 4; ++nt) {
                const size_t off = wt_base + (size_t)(wv * 64 + nt * 16 + l15) * fan
                                 + (size_t)(k0 + kh) + (size_t)(g4 * 8);
                bfr[nt] = *(const bf16x8*)&g_Wt[off];
            }
            #pragma unroll
            for (int t = 0; t < 3; ++t)
                #pragma unroll
                for (int nt = 0; nt < 4; ++nt)
                    acc[t][nt] = __builtin_amdgcn_mfma_f32_16x16x32_bf16(a[t], bfr[nt], acc[t][nt], 0, 0, 0);
        }
    }

    // C/D layout (m89-verified): col = lane&15, row = (lane>>4)*4 + reg
    #pragma unroll
    for (int t = 0; t < 3; ++t) {
        #pragma unroll
        for (int reg = 0; reg < 4; ++reg) {
            const int mrow = t * 16 + g4 * 4 + reg;  // = b*3 + i
            const int b = mrow / 3;
            const int i = mrow - b * 3;
            #pragma unroll
            for (int nt = 0; nt < 4; ++nt) {
                const int o = wv * 64 + nt * 16 + l15;
                out[(((size_t)b * NRES + p) * ODIM + o) * 3 + i] = acc[t][nt][reg];
            }
        }
    }
}

extern "C" void kernel_launch(void* const* d_in, const int* in_sizes, int n_in,
                              void* d_out, int out_size, void* d_ws, size_t ws_size,
                              hipStream_t stream) {
    (void)n_in; (void)out_size; (void)d_ws; (void)ws_size;
    const float* x = (const float*)d_in[0];
    const float* W = (const float*)d_in[1];
    float* out = (float*)d_out;
    // atoms from runtime size (should equal H_META.atoms); used only for batch stride
    const int atoms = in_sizes[0] / (NB * ADIM * 3);
    prep_W_kernel<<<TOTROWS, 256, 0, stream>>>(W);
    lin_mfma_kernel<<<NRES, 256, 0, stream>>>(x, out, atoms);
}